// Round 1
// baseline (585.371 us; speedup 1.0000x reference)
//
#include <hip/hip_runtime.h>

// AdaptiveEmbedding: T=16384 tokens -> bucket by cluster -> 4 batched GEMMs.
// Input order (setup_inputs dict): inp, emb0, proj0, emb1, proj1, emb2, proj2, emb3, proj3
// emb_i: [size_i, K_i] fp32 row-major; proj_i: [1024, K_i] fp32 row-major.
// out[t, p] = 32.0 * sum_k emb_i[id - l][k] * proj_i[p][k]
//
// ws layout: [0..16)  4x u32 cluster counters (zeroed via hipMemsetAsync)
//            [256..)  4 packed lists of T u32 each: (t << 18) | (id - l)
//            (idx < 2^18 since max cluster size 160000; t < 2^14)

#define CUT0 20000
#define CUT1 40000
#define CUT2 200000

__global__ __launch_bounds__(256)
void classify_kernel(const int* __restrict__ inp, unsigned* __restrict__ counters,
                     unsigned* __restrict__ lists, int T) {
    int t = blockIdx.x * 256 + threadIdx.x;
    if (t >= T) return;
    int id = inp[t];
    int c, l;
    if (id < CUT0)      { c = 0; l = 0; }
    else if (id < CUT1) { c = 1; l = CUT0; }
    else if (id < CUT2) { c = 2; l = CUT1; }
    else                { c = 3; l = CUT2; }
    unsigned pos = atomicAdd(&counters[c], 1u);
    lists[(size_t)c * T + pos] = ((unsigned)t << 18) | (unsigned)(id - l);
}

// Tiled GEMM over one cluster's token list.
// Tile: TM=32 tokens x TN=64 output cols, block = 256 threads (16x16),
// each thread computes a 2x4 micro-tile. K chunked at KB.
template<int K, int KB>
__global__ __launch_bounds__(256)
void gemm_kernel(const float* __restrict__ emb, const float* __restrict__ proj,
                 const unsigned* __restrict__ list, const unsigned* __restrict__ counters,
                 int cidx, float* __restrict__ out) {
    constexpr int EP = KB + 1;         // E LDS pitch (pad +1: conflict-free)
    __shared__ float E_s[32 * EP];     // [row][k]
    __shared__ float P_s[KB * 65];     // [k][col], pitch 65
    __shared__ unsigned pk_s[32];

    const int count = (int)counters[cidx];
    const int m0 = blockIdx.x * 32;
    if (m0 >= count) return;           // uniform exit for surplus blocks
    const int rows = min(32, count - m0);
    const int py = blockIdx.y * 64;
    const int tid = (int)threadIdx.x;
    const int tx = tid & 15, ty = tid >> 4;

    if (tid < 32) pk_s[tid] = (tid < rows) ? list[m0 + tid] : 0u;
    __syncthreads();

    float acc[2][4] = {{0.f,0.f,0.f,0.f},{0.f,0.f,0.f,0.f}};

    for (int kk = 0; kk < K; kk += KB) {
        // Stage E chunk: rows x KB, coalesced float4 per row segment.
        for (int i = tid; i < 32 * (KB / 4); i += 256) {
            int r = i / (KB / 4), q = i % (KB / 4);
            if (r < rows) {
                int idx = (int)(pk_s[r] & 0x3FFFFu);
                float4 v = *(const float4*)(emb + (size_t)idx * K + kk + q * 4);
                float* d = &E_s[r * EP + q * 4];
                d[0] = v.x; d[1] = v.y; d[2] = v.z; d[3] = v.w;
            }
        }
        // Stage P chunk: 64 cols x KB, transposed into [k][col] (pitch 65).
        for (int i = tid; i < 64 * (KB / 4); i += 256) {
            int p = i / (KB / 4), q = i % (KB / 4);
            float4 v = *(const float4*)(proj + (size_t)(py + p) * K + kk + q * 4);
            P_s[(q * 4 + 0) * 65 + p] = v.x;
            P_s[(q * 4 + 1) * 65 + p] = v.y;
            P_s[(q * 4 + 2) * 65 + p] = v.z;
            P_s[(q * 4 + 3) * 65 + p] = v.w;
        }
        __syncthreads();

        #pragma unroll
        for (int k = 0; k < KB; ++k) {
            float a0 = E_s[(ty * 2 + 0) * EP + k];
            float a1 = E_s[(ty * 2 + 1) * EP + k];
            float b0 = P_s[k * 65 + tx * 4 + 0];
            float b1 = P_s[k * 65 + tx * 4 + 1];
            float b2 = P_s[k * 65 + tx * 4 + 2];
            float b3 = P_s[k * 65 + tx * 4 + 3];
            acc[0][0] = fmaf(a0, b0, acc[0][0]);
            acc[0][1] = fmaf(a0, b1, acc[0][1]);
            acc[0][2] = fmaf(a0, b2, acc[0][2]);
            acc[0][3] = fmaf(a0, b3, acc[0][3]);
            acc[1][0] = fmaf(a1, b0, acc[1][0]);
            acc[1][1] = fmaf(a1, b1, acc[1][1]);
            acc[1][2] = fmaf(a1, b2, acc[1][2]);
            acc[1][3] = fmaf(a1, b3, acc[1][3]);
        }
        __syncthreads();
    }

    #pragma unroll
    for (int i = 0; i < 2; ++i) {
        int r = ty * 2 + i;
        if (r < rows) {
            int t = (int)(pk_s[r] >> 18);
            float4 o;
            o.x = acc[i][0] * 32.0f;   // EMB_SCALE = sqrt(1024) = 32 exactly
            o.y = acc[i][1] * 32.0f;
            o.z = acc[i][2] * 32.0f;
            o.w = acc[i][3] * 32.0f;
            *(float4*)(out + (size_t)t * 1024 + py + tx * 4) = o;
        }
    }
}

extern "C" void kernel_launch(void* const* d_in, const int* in_sizes, int n_in,
                              void* d_out, int out_size, void* d_ws, size_t ws_size,
                              hipStream_t stream) {
    const int*   inp   = (const int*)d_in[0];
    const float* emb0  = (const float*)d_in[1];
    const float* proj0 = (const float*)d_in[2];
    const float* emb1  = (const float*)d_in[3];
    const float* proj1 = (const float*)d_in[4];
    const float* emb2  = (const float*)d_in[5];
    const float* proj2 = (const float*)d_in[6];
    const float* emb3  = (const float*)d_in[7];
    const float* proj3 = (const float*)d_in[8];
    float* out = (float*)d_out;
    const int T = in_sizes[0];   // 16384

    unsigned* counters = (unsigned*)d_ws;
    unsigned* lists    = (unsigned*)((char*)d_ws + 256);

    hipMemsetAsync(counters, 0, 16, stream);
    classify_kernel<<<dim3((T + 255) / 256), 256, 0, stream>>>(inp, counters, lists, T);

    dim3 grid((T + 31) / 32, 16);   // 512 token-tiles (worst case) x 16 col-tiles
    gemm_kernel<1024, 64><<<grid, 256, 0, stream>>>(emb0, proj0, lists + 0 * (size_t)T, counters, 0, out);
    gemm_kernel< 256, 64><<<grid, 256, 0, stream>>>(emb1, proj1, lists + 1 * (size_t)T, counters, 1, out);
    gemm_kernel<  64, 64><<<grid, 256, 0, stream>>>(emb2, proj2, lists + 2 * (size_t)T, counters, 2, out);
    gemm_kernel<  16, 16><<<grid, 256, 0, stream>>>(emb3, proj3, lists + 3 * (size_t)T, counters, 3, out);
}

// Round 2
// 473.787 us; speedup vs baseline: 1.2355x; 1.2355x over previous
//
#include <hip/hip_runtime.h>

// AdaptiveEmbedding: bucket tokens by cluster -> 4 batched GEMMs (fp32 VALU).
// Inputs: inp, emb0, proj0, emb1, proj1, emb2, proj2, emb3, proj3
// emb_i: [size_i, K_i] fp32 row-major; proj_i: [1024, K_i] fp32 row-major.
// out[t, p] = 32.0 * sum_k emb_i[id - l][k] * proj_i[p][k]
//
// ws: [0..16) 4x u32 counters (zeroed async); [256..) 4 lists of T u32:
//     (t << 18) | (id - l)   (idx < 2^18, t < 2^14)
//
// GEMM structure (round 2): 64 tokens x 64 cols per block, 256 threads,
// 4x4 micro-tile, k in quads of 4. Per k-quad per thread: 8 ds_read_b128
// (~96 cyc/wave) vs 64 fmaf (128 cyc/wave) -> VALU-issue-bound.
// E_s[row][k] pitch KB+4 (16B aligned, 2-way banks = free).
// P_s[k][col] pitch 64 (aligned reads 2-way; staging writes conflict-free
// because col = lane&63 varies fastest).

#define CUT0 20000
#define CUT1 40000
#define CUT2 200000

__global__ __launch_bounds__(256)
void classify_kernel(const int* __restrict__ inp, unsigned* __restrict__ counters,
                     unsigned* __restrict__ lists, int T) {
    int t = blockIdx.x * 256 + threadIdx.x;
    if (t >= T) return;
    int id = inp[t];
    int c, l;
    if (id < CUT0)      { c = 0; l = 0; }
    else if (id < CUT1) { c = 1; l = CUT0; }
    else if (id < CUT2) { c = 2; l = CUT1; }
    else                { c = 3; l = CUT2; }
    unsigned pos = atomicAdd(&counters[c], 1u);
    lists[(size_t)c * T + pos] = ((unsigned)t << 18) | (unsigned)(id - l);
}

#define FMA4(A, B, C) \
    C.x = fmaf(A, B.x, C.x); C.y = fmaf(A, B.y, C.y); \
    C.z = fmaf(A, B.z, C.z); C.w = fmaf(A, B.w, C.w)

template<int K, int KB>
__global__ __launch_bounds__(256)
void gemm_kernel(const float* __restrict__ emb, const float* __restrict__ proj,
                 const unsigned* __restrict__ list, const unsigned* __restrict__ counters,
                 int cidx, float* __restrict__ out) {
    constexpr int EP = KB + 4;                 // E pitch: 16B-aligned, bank-safe
    constexpr int QR = KB / 4;                 // k-quads per row
    __shared__ __align__(16) float E_s[64 * EP];   // [row][k]
    __shared__ __align__(16) float P_s[KB * 64];   // [k][col]
    __shared__ unsigned pk_s[64];

    const int count = (int)counters[cidx];
    const int m0 = blockIdx.x * 64;
    if (m0 >= count) return;                   // block-uniform exit
    const int rows = min(64, count - m0);
    const int py = blockIdx.y * 64;
    const int tid = (int)threadIdx.x;
    const int tx = tid & 15, ty = tid >> 4;
    const int pcol = tid & 63;                 // P staging: col fastest across lanes
    const int pq0  = tid >> 6;                 // P staging: quad 0..3

    if (tid < 64) pk_s[tid] = (tid < rows) ? list[m0 + tid] : 0u;
    __syncthreads();

    float4 acc[4] = {};                        // acc[i] = row ty*4+i, cols tx*4..+3

    for (int kk = 0; kk < K; kk += KB) {
        // Stage E: 64 rows x KB, coalesced float4 along k, b128 LDS writes.
        #pragma unroll
        for (int it = 0; it < (64 * QR) / 256; ++it) {
            int item = tid + it * 256;
            int r = item / QR, q = item % QR;
            if (r < rows) {
                int idx = (int)(pk_s[r] & 0x3FFFFu);
                float4 v = *(const float4*)(emb + (size_t)idx * K + kk + q * 4);
                *(float4*)&E_s[r * EP + q * 4] = v;
            }
        }
        // Stage P transposed: [k][col]. Global read is scattered across 64
        // rows (L2-served, proj chunk is hot); LDS writes conflict-free.
        #pragma unroll
        for (int it = 0; it < QR / 4; ++it) {
            int q = pq0 + it * 4;
            float4 v = *(const float4*)(proj + (size_t)(py + pcol) * K + kk + q * 4);
            P_s[(q * 4 + 0) * 64 + pcol] = v.x;
            P_s[(q * 4 + 1) * 64 + pcol] = v.y;
            P_s[(q * 4 + 2) * 64 + pcol] = v.z;
            P_s[(q * 4 + 3) * 64 + pcol] = v.w;
        }
        __syncthreads();

        #pragma unroll
        for (int kq = 0; kq < KB; kq += 4) {
            float4 a0 = *(const float4*)&E_s[(ty * 4 + 0) * EP + kq];
            float4 a1 = *(const float4*)&E_s[(ty * 4 + 1) * EP + kq];
            float4 a2 = *(const float4*)&E_s[(ty * 4 + 2) * EP + kq];
            float4 a3 = *(const float4*)&E_s[(ty * 4 + 3) * EP + kq];
            float4 b0 = *(const float4*)&P_s[(kq + 0) * 64 + tx * 4];
            float4 b1 = *(const float4*)&P_s[(kq + 1) * 64 + tx * 4];
            float4 b2 = *(const float4*)&P_s[(kq + 2) * 64 + tx * 4];
            float4 b3 = *(const float4*)&P_s[(kq + 3) * 64 + tx * 4];
            FMA4(a0.x, b0, acc[0]); FMA4(a0.y, b1, acc[0]);
            FMA4(a0.z, b2, acc[0]); FMA4(a0.w, b3, acc[0]);
            FMA4(a1.x, b0, acc[1]); FMA4(a1.y, b1, acc[1]);
            FMA4(a1.z, b2, acc[1]); FMA4(a1.w, b3, acc[1]);
            FMA4(a2.x, b0, acc[2]); FMA4(a2.y, b1, acc[2]);
            FMA4(a2.z, b2, acc[2]); FMA4(a2.w, b3, acc[2]);
            FMA4(a3.x, b0, acc[3]); FMA4(a3.y, b1, acc[3]);
            FMA4(a3.z, b2, acc[3]); FMA4(a3.w, b3, acc[3]);
        }
        __syncthreads();
    }

    #pragma unroll
    for (int i = 0; i < 4; ++i) {
        int r = ty * 4 + i;
        if (r < rows) {
            int t = (int)(pk_s[r] >> 18);
            float4 o;
            o.x = acc[i].x * 32.0f;            // EMB_SCALE = sqrt(1024) = 32
            o.y = acc[i].y * 32.0f;
            o.z = acc[i].z * 32.0f;
            o.w = acc[i].w * 32.0f;
            *(float4*)(out + (size_t)t * 1024 + py + tx * 4) = o;
        }
    }
}

extern "C" void kernel_launch(void* const* d_in, const int* in_sizes, int n_in,
                              void* d_out, int out_size, void* d_ws, size_t ws_size,
                              hipStream_t stream) {
    const int*   inp   = (const int*)d_in[0];
    const float* emb0  = (const float*)d_in[1];
    const float* proj0 = (const float*)d_in[2];
    const float* emb1  = (const float*)d_in[3];
    const float* proj1 = (const float*)d_in[4];
    const float* emb2  = (const float*)d_in[5];
    const float* proj2 = (const float*)d_in[6];
    const float* emb3  = (const float*)d_in[7];
    const float* proj3 = (const float*)d_in[8];
    float* out = (float*)d_out;
    const int T = in_sizes[0];   // 16384

    unsigned* counters = (unsigned*)d_ws;
    unsigned* lists    = (unsigned*)((char*)d_ws + 256);

    hipMemsetAsync(counters, 0, 16, stream);
    classify_kernel<<<dim3((T + 255) / 256), 256, 0, stream>>>(inp, counters, lists, T);

    dim3 grid((T + 63) / 64, 16);   // 256 token-tiles (worst case) x 16 col-tiles
    gemm_kernel<1024, 64><<<grid, 256, 0, stream>>>(emb0, proj0, lists + 0 * (size_t)T, counters, 0, out);
    gemm_kernel< 256, 64><<<grid, 256, 0, stream>>>(emb1, proj1, lists + 1 * (size_t)T, counters, 1, out);
    gemm_kernel<  64, 64><<<grid, 256, 0, stream>>>(emb2, proj2, lists + 2 * (size_t)T, counters, 2, out);
    gemm_kernel<  16, 16><<<grid, 256, 0, stream>>>(emb3, proj3, lists + 3 * (size_t)T, counters, 3, out);
}

// Round 3
// 291.820 us; speedup vs baseline: 2.0059x; 1.6236x over previous
//
#include <hip/hip_runtime.h>

// AdaptiveEmbedding: bucket tokens by cluster (wave-aggregated atomics) ->
// 4 batched bf16-MFMA GEMMs.
// Inputs: inp, emb0, proj0, emb1, proj1, emb2, proj2, emb3, proj3
// emb_i: [size_i, K_i] fp32 row-major; proj_i: [1024, K_i] fp32 row-major.
// out[t, p] = 32.0 * sum_k emb_i[id - l][k] * proj_i[p][k]
//   == E . proj^T  -> both MFMA operands are [row][k] row-major (gemm_bt).
//
// ws: [0..16) 4x u32 counters (zeroed async); [256..) 4 lists of T u32:
//     (t << 18) | (id - l)
//
// GEMM: 64 tokens x 64 cols per block, 256 threads = 4 waves; wave w owns
// rows w*16..+16 x all 64 cols as 4 accumulators of 16x16 (f32x4 each).
// K chunked at 64 (K=16 zero-padded to one 32-k MFMA step).
// LDS bf16 pitch 72 (144B = 9x16B: aligned b128, (row+quad)%8 bank spread).

#define CUT0 20000
#define CUT1 40000
#define CUT2 200000

typedef __attribute__((ext_vector_type(8))) short bf16x8;
typedef __attribute__((ext_vector_type(8))) unsigned short u16x8;
typedef __attribute__((ext_vector_type(4))) unsigned short u16x4;
typedef __attribute__((ext_vector_type(4))) float f32x4;

__device__ __forceinline__ unsigned short f2bf(float f) {
    unsigned u = __float_as_uint(f);
    u += 0x7FFFu + ((u >> 16) & 1u);   // round-to-nearest-even
    return (unsigned short)(u >> 16);
}

__global__ __launch_bounds__(256)
void classify_kernel(const int* __restrict__ inp, unsigned* __restrict__ counters,
                     unsigned* __restrict__ lists, int T) {
    int t = blockIdx.x * 256 + threadIdx.x;
    int lane = threadIdx.x & 63;
    bool valid = (t < T);
    int id = valid ? inp[t] : 0;
    int c = -1, l = 0;
    if (valid) {
        if (id < CUT0)      { c = 0; l = 0; }
        else if (id < CUT1) { c = 1; l = CUT0; }
        else if (id < CUT2) { c = 2; l = CUT1; }
        else                { c = 3; l = CUT2; }
    }
    #pragma unroll
    for (int i = 0; i < 4; ++i) {
        unsigned long long m = __ballot(c == i);
        if (c == i) {
            int leader = __ffsll(m) - 1;
            unsigned base = 0;
            if (lane == leader) base = atomicAdd(&counters[i], (unsigned)__popcll(m));
            base = __shfl(base, leader);
            unsigned rank = (unsigned)__popcll(m & ((1ull << lane) - 1ull));
            lists[(size_t)i * T + base + rank] = ((unsigned)t << 18) | (unsigned)(id - l);
        }
    }
}

template<int K>
__global__ __launch_bounds__(256)
void gemm_mfma(const float* __restrict__ emb, const float* __restrict__ proj,
               const unsigned* __restrict__ list, const unsigned* __restrict__ counters,
               int cidx, float* __restrict__ out) {
    constexpr int KB  = (K >= 64) ? 64 : K;   // k-chunk in LDS
    constexpr int NCH = K / KB;
    constexpr int KSTEPS = (KB + 31) / 32;    // MFMA k-steps per chunk
    constexpr int PITCH = 72;                 // bf16 elems: 144B row pitch
    __shared__ unsigned short E_s[64 * PITCH];
    __shared__ unsigned short P_s[64 * PITCH];
    __shared__ unsigned pk_s[64];

    const int count = (int)counters[cidx];
    const int m0 = blockIdx.x * 64;
    if (m0 >= count) return;                  // block-uniform exit
    const int rows = min(64, count - m0);
    const int py = blockIdx.y * 64;
    const int tid = (int)threadIdx.x;
    const int lane = tid & 63;
    const int w  = tid >> 6;                  // wave id 0..3
    const int ln = lane & 15;
    const int qd = lane >> 4;                 // quad 0..3
    const int sr = tid >> 2;                  // staging row 0..63
    const int sq = tid & 3;                   // staging k-quarter 0..3

    if (tid < 64) pk_s[tid] = (tid < rows) ? list[m0 + tid] : 0u;
    __syncthreads();

    f32x4 acc[4];
    #pragma unroll
    for (int ct = 0; ct < 4; ++ct) acc[ct] = (f32x4){0.f, 0.f, 0.f, 0.f};

    const size_t erow = (size_t)(pk_s[sr] & 0x3FFFFu) * K;  // row 0 for sr>=rows: safe
    const size_t prow = (size_t)(py + sr) * K;

    for (int ch = 0; ch < NCH; ++ch) {
        const int kk = ch * KB;
        if constexpr (KB == 64) {
            // 16 fp32 per thread from each of E and P; 4 lanes cover one row.
            const float* es = emb + erow + kk + sq * 16;
            const float* ps = proj + prow + kk + sq * 16;
            float4 e0 = *(const float4*)(es);
            float4 e1 = *(const float4*)(es + 4);
            float4 e2 = *(const float4*)(es + 8);
            float4 e3 = *(const float4*)(es + 12);
            float4 p0 = *(const float4*)(ps);
            float4 p1 = *(const float4*)(ps + 4);
            float4 p2 = *(const float4*)(ps + 8);
            float4 p3 = *(const float4*)(ps + 12);
            u16x8 eh0 = {f2bf(e0.x), f2bf(e0.y), f2bf(e0.z), f2bf(e0.w),
                         f2bf(e1.x), f2bf(e1.y), f2bf(e1.z), f2bf(e1.w)};
            u16x8 eh1 = {f2bf(e2.x), f2bf(e2.y), f2bf(e2.z), f2bf(e2.w),
                         f2bf(e3.x), f2bf(e3.y), f2bf(e3.z), f2bf(e3.w)};
            u16x8 ph0 = {f2bf(p0.x), f2bf(p0.y), f2bf(p0.z), f2bf(p0.w),
                         f2bf(p1.x), f2bf(p1.y), f2bf(p1.z), f2bf(p1.w)};
            u16x8 ph1 = {f2bf(p2.x), f2bf(p2.y), f2bf(p2.z), f2bf(p2.w),
                         f2bf(p3.x), f2bf(p3.y), f2bf(p3.z), f2bf(p3.w)};
            *(u16x8*)&E_s[sr * PITCH + sq * 16]     = eh0;
            *(u16x8*)&E_s[sr * PITCH + sq * 16 + 8] = eh1;
            *(u16x8*)&P_s[sr * PITCH + sq * 16]     = ph0;
            *(u16x8*)&P_s[sr * PITCH + sq * 16 + 8] = ph1;
        } else {
            // KB == 16: 4 fp32 per thread; zero-pad k 16..31 for the 32-k MFMA.
            float4 e0 = *(const float4*)(emb + erow + sq * 4);
            float4 p0 = *(const float4*)(proj + prow + sq * 4);
            u16x4 eh = {f2bf(e0.x), f2bf(e0.y), f2bf(e0.z), f2bf(e0.w)};
            u16x4 ph = {f2bf(p0.x), f2bf(p0.y), f2bf(p0.z), f2bf(p0.w)};
            u16x4 z  = {0, 0, 0, 0};
            *(u16x4*)&E_s[sr * PITCH + sq * 4]      = eh;
            *(u16x4*)&E_s[sr * PITCH + 16 + sq * 4] = z;
            *(u16x4*)&P_s[sr * PITCH + sq * 4]      = ph;
            *(u16x4*)&P_s[sr * PITCH + 16 + sq * 4] = z;
        }
        __syncthreads();

        const unsigned short* ea = &E_s[(w * 16 + ln) * PITCH + qd * 8];
        const unsigned short* pb = &P_s[ln * PITCH + qd * 8];
        #pragma unroll
        for (int s = 0; s < KSTEPS; ++s) {
            bf16x8 a = *(const bf16x8*)(ea + s * 32);
            #pragma unroll
            for (int ct = 0; ct < 4; ++ct) {
                bf16x8 b = *(const bf16x8*)(pb + ct * 16 * PITCH + s * 32);
                acc[ct] = __builtin_amdgcn_mfma_f32_16x16x32_bf16(a, b, acc[ct], 0, 0, 0);
            }
        }
        __syncthreads();
    }

    // C/D layout: col = lane&15, row = (lane>>4)*4 + reg   [m89/m91]
    #pragma unroll
    for (int ct = 0; ct < 4; ++ct) {
        #pragma unroll
        for (int r = 0; r < 4; ++r) {
            int row = w * 16 + qd * 4 + r;
            if (row < rows) {
                int t = (int)(pk_s[row] >> 18);
                out[(size_t)t * 1024 + py + ct * 16 + ln] = acc[ct][r] * 32.0f;
            }
        }
    }
}

extern "C" void kernel_launch(void* const* d_in, const int* in_sizes, int n_in,
                              void* d_out, int out_size, void* d_ws, size_t ws_size,
                              hipStream_t stream) {
    const int*   inp   = (const int*)d_in[0];
    const float* emb0  = (const float*)d_in[1];
    const float* proj0 = (const float*)d_in[2];
    const float* emb1  = (const float*)d_in[3];
    const float* proj1 = (const float*)d_in[4];
    const float* emb2  = (const float*)d_in[5];
    const float* proj2 = (const float*)d_in[6];
    const float* emb3  = (const float*)d_in[7];
    const float* proj3 = (const float*)d_in[8];
    float* out = (float*)d_out;
    const int T = in_sizes[0];   // 16384

    unsigned* counters = (unsigned*)d_ws;
    unsigned* lists    = (unsigned*)((char*)d_ws + 256);

    hipMemsetAsync(counters, 0, 16, stream);
    classify_kernel<<<dim3((T + 255) / 256), 256, 0, stream>>>(inp, counters, lists, T);

    dim3 grid((T + 63) / 64, 16);   // worst-case token tiles x 16 col-tiles
    gemm_mfma<1024><<<grid, 256, 0, stream>>>(emb0, proj0, lists + 0 * (size_t)T, counters, 0, out);
    gemm_mfma< 256><<<grid, 256, 0, stream>>>(emb1, proj1, lists + 1 * (size_t)T, counters, 1, out);
    gemm_mfma<  64><<<grid, 256, 0, stream>>>(emb2, proj2, lists + 2 * (size_t)T, counters, 2, out);
    gemm_mfma<  16><<<grid, 256, 0, stream>>>(emb3, proj3, lists + 3 * (size_t)T, counters, 3, out);
}

// Round 4
// 228.099 us; speedup vs baseline: 2.5663x; 1.2794x over previous
//
#include <hip/hip_runtime.h>

// AdaptiveEmbedding: bucket tokens by cluster (wave-aggregated atomics) ->
// ONE fused persistent bf16-MFMA GEMM over all 4 clusters' tiles.
// Inputs: inp, emb0, proj0, emb1, proj1, emb2, proj2, emb3, proj3
// emb_i: [size_i, K_i] fp32 row-major; proj_i: [1024, K_i] fp32 row-major.
// out[t, p] = 32.0 * sum_k emb_i[id - l][k] * proj_i[p][k]
//   == E . proj^T  -> both MFMA operands are [row][k] row-major (gemm_bt).
//
// ws: [0..16) 4x u32 counters (zeroed async); [256..) 4 lists of T u32:
//     (t << 18) | (id - l)
//
// Round 4: the 4 separate gemm dispatches were each latency-bound at
// ~1 block/CU (gemm0: 320 blocks, occupancy 9%, all pipes <5%) and ran
// SEQUENTIALLY. Fused persistent kernel grid-strides a flat tile id over
// all clusters (~4100 tiles on 2048 blocks) -> all clusters concurrent,
// ~16 tiles/CU of real work to hide gather latency.
// Tile: 64 tokens x 64 cols, 256 threads = 4 waves, K chunked at 64
// (K=16 zero-padded to one 32-k MFMA step). LDS bf16 pitch 72.

#define CUT0 20000
#define CUT1 40000
#define CUT2 200000

typedef __attribute__((ext_vector_type(8))) short bf16x8;
typedef __attribute__((ext_vector_type(8))) unsigned short u16x8;
typedef __attribute__((ext_vector_type(4))) unsigned short u16x4;
typedef __attribute__((ext_vector_type(4))) float f32x4;

__device__ __forceinline__ unsigned short f2bf(float f) {
    unsigned u = __float_as_uint(f);
    u += 0x7FFFu + ((u >> 16) & 1u);   // round-to-nearest-even
    return (unsigned short)(u >> 16);
}

__global__ __launch_bounds__(256)
void classify_kernel(const int* __restrict__ inp, unsigned* __restrict__ counters,
                     unsigned* __restrict__ lists, int T) {
    int t = blockIdx.x * 256 + threadIdx.x;
    int lane = threadIdx.x & 63;
    bool valid = (t < T);
    int id = valid ? inp[t] : 0;
    int c = -1, l = 0;
    if (valid) {
        if (id < CUT0)      { c = 0; l = 0; }
        else if (id < CUT1) { c = 1; l = CUT0; }
        else if (id < CUT2) { c = 2; l = CUT1; }
        else                { c = 3; l = CUT2; }
    }
    #pragma unroll
    for (int i = 0; i < 4; ++i) {
        unsigned long long m = __ballot(c == i);
        if (c == i) {
            int leader = __ffsll(m) - 1;
            unsigned base = 0;
            if (lane == leader) base = atomicAdd(&counters[i], (unsigned)__popcll(m));
            base = __shfl(base, leader);
            unsigned rank = (unsigned)__popcll(m & ((1ull << lane) - 1ull));
            lists[(size_t)i * T + base + rank] = ((unsigned)t << 18) | (unsigned)(id - l);
        }
    }
}

#define PITCH 72   // bf16 elems per LDS row: 144B = 9x16B (aligned b128)

template<int K>
__device__ __forceinline__
void tile_gemm(const float* __restrict__ emb, const float* __restrict__ proj,
               const unsigned* __restrict__ list, int count, int mtile, int ntile,
               float* __restrict__ out,
               unsigned short* E_s, unsigned short* P_s, unsigned* pk_s) {
    constexpr int KB  = (K >= 64) ? 64 : K;
    constexpr int NCH = K / KB;
    constexpr int KSTEPS = (KB + 31) / 32;

    const int m0 = mtile * 64;
    const int rows = min(64, count - m0);
    const int py = ntile * 64;
    const int tid = (int)threadIdx.x;
    const int lane = tid & 63;
    const int w  = tid >> 6;                  // wave id 0..3
    const int ln = lane & 15;
    const int qd = lane >> 4;                 // quad 0..3
    const int sr = tid >> 2;                  // staging row 0..63
    const int sq = tid & 3;                   // staging k-quarter 0..3

    if (tid < 64) pk_s[tid] = (tid < rows) ? list[m0 + tid] : 0u;
    __syncthreads();

    f32x4 acc[4];
    #pragma unroll
    for (int ct = 0; ct < 4; ++ct) acc[ct] = (f32x4){0.f, 0.f, 0.f, 0.f};

    const size_t erow = (size_t)(pk_s[sr] & 0x3FFFFu) * K;  // row 0 if sr>=rows: safe
    const size_t prow = (size_t)(py + sr) * K;

    for (int ch = 0; ch < NCH; ++ch) {
        const int kk = ch * KB;
        if constexpr (KB == 64) {
            const float* es = emb + erow + kk + sq * 16;
            const float* ps = proj + prow + kk + sq * 16;
            float4 e0 = *(const float4*)(es);
            float4 e1 = *(const float4*)(es + 4);
            float4 e2 = *(const float4*)(es + 8);
            float4 e3 = *(const float4*)(es + 12);
            float4 p0 = *(const float4*)(ps);
            float4 p1 = *(const float4*)(ps + 4);
            float4 p2 = *(const float4*)(ps + 8);
            float4 p3 = *(const float4*)(ps + 12);
            u16x8 eh0 = {f2bf(e0.x), f2bf(e0.y), f2bf(e0.z), f2bf(e0.w),
                         f2bf(e1.x), f2bf(e1.y), f2bf(e1.z), f2bf(e1.w)};
            u16x8 eh1 = {f2bf(e2.x), f2bf(e2.y), f2bf(e2.z), f2bf(e2.w),
                         f2bf(e3.x), f2bf(e3.y), f2bf(e3.z), f2bf(e3.w)};
            u16x8 ph0 = {f2bf(p0.x), f2bf(p0.y), f2bf(p0.z), f2bf(p0.w),
                         f2bf(p1.x), f2bf(p1.y), f2bf(p1.z), f2bf(p1.w)};
            u16x8 ph1 = {f2bf(p2.x), f2bf(p2.y), f2bf(p2.z), f2bf(p2.w),
                         f2bf(p3.x), f2bf(p3.y), f2bf(p3.z), f2bf(p3.w)};
            *(u16x8*)&E_s[sr * PITCH + sq * 16]     = eh0;
            *(u16x8*)&E_s[sr * PITCH + sq * 16 + 8] = eh1;
            *(u16x8*)&P_s[sr * PITCH + sq * 16]     = ph0;
            *(u16x8*)&P_s[sr * PITCH + sq * 16 + 8] = ph1;
        } else {
            // KB == 16: zero-pad k 16..31 for the single 32-k MFMA step.
            float4 e0 = *(const float4*)(emb + erow + sq * 4);
            float4 p0 = *(const float4*)(proj + prow + sq * 4);
            u16x4 eh = {f2bf(e0.x), f2bf(e0.y), f2bf(e0.z), f2bf(e0.w)};
            u16x4 ph = {f2bf(p0.x), f2bf(p0.y), f2bf(p0.z), f2bf(p0.w)};
            u16x4 z  = {0, 0, 0, 0};
            *(u16x4*)&E_s[sr * PITCH + sq * 4]      = eh;
            *(u16x4*)&E_s[sr * PITCH + 16 + sq * 4] = z;
            *(u16x4*)&P_s[sr * PITCH + sq * 4]      = ph;
            *(u16x4*)&P_s[sr * PITCH + 16 + sq * 4] = z;
        }
        __syncthreads();

        const unsigned short* ea = &E_s[(w * 16 + ln) * PITCH + qd * 8];
        const unsigned short* pb = &P_s[ln * PITCH + qd * 8];
        #pragma unroll
        for (int s = 0; s < KSTEPS; ++s) {
            bf16x8 a = *(const bf16x8*)(ea + s * 32);
            #pragma unroll
            for (int ct = 0; ct < 4; ++ct) {
                bf16x8 b = *(const bf16x8*)(pb + ct * 16 * PITCH + s * 32);
                acc[ct] = __builtin_amdgcn_mfma_f32_16x16x32_bf16(a, b, acc[ct], 0, 0, 0);
            }
        }
        __syncthreads();
    }

    // C/D layout: col = lane&15, row = (lane>>4)*4 + reg   [m89/m91]
    #pragma unroll
    for (int ct = 0; ct < 4; ++ct) {
        #pragma unroll
        for (int r = 0; r < 4; ++r) {
            int row = w * 16 + qd * 4 + r;
            if (row < rows) {
                int t = (int)(pk_s[row] >> 18);
                out[(size_t)t * 1024 + py + ct * 16 + ln] = acc[ct][r] * 32.0f;
            }
        }
    }
    __syncthreads();   // protect pk_s/LDS before next tile overwrites
}

__global__ __launch_bounds__(256)
void gemm_fused(const float* __restrict__ emb0, const float* __restrict__ proj0,
                const float* __restrict__ emb1, const float* __restrict__ proj1,
                const float* __restrict__ emb2, const float* __restrict__ proj2,
                const float* __restrict__ emb3, const float* __restrict__ proj3,
                const unsigned* __restrict__ lists, const unsigned* __restrict__ counters,
                int T, float* __restrict__ out) {
    __shared__ unsigned short E_s[64 * PITCH];
    __shared__ unsigned short P_s[64 * PITCH];
    __shared__ unsigned pk_s[64];

    const int c0 = (int)counters[0], c1 = (int)counters[1];
    const int c2 = (int)counters[2], c3 = (int)counters[3];
    const int e0t = ((c0 + 63) >> 6) * 16;          // tiles end, cluster 0
    const int e1t = e0t + ((c1 + 63) >> 6) * 16;
    const int e2t = e1t + ((c2 + 63) >> 6) * 16;
    const int e3t = e2t + ((c3 + 63) >> 6) * 16;

    for (int tile = blockIdx.x; tile < e3t; tile += gridDim.x) {
        // cluster-major; col-tiles consecutive per m-tile (E-row L3 locality)
        if (tile < e0t) {
            int lt = tile;
            tile_gemm<1024>(emb0, proj0, lists + 0 * (size_t)T, c0, lt >> 4, lt & 15, out, E_s, P_s, pk_s);
        } else if (tile < e1t) {
            int lt = tile - e0t;
            tile_gemm< 256>(emb1, proj1, lists + 1 * (size_t)T, c1, lt >> 4, lt & 15, out, E_s, P_s, pk_s);
        } else if (tile < e2t) {
            int lt = tile - e1t;
            tile_gemm<  64>(emb2, proj2, lists + 2 * (size_t)T, c2, lt >> 4, lt & 15, out, E_s, P_s, pk_s);
        } else {
            int lt = tile - e2t;
            tile_gemm<  16>(emb3, proj3, lists + 3 * (size_t)T, c3, lt >> 4, lt & 15, out, E_s, P_s, pk_s);
        }
    }
}

extern "C" void kernel_launch(void* const* d_in, const int* in_sizes, int n_in,
                              void* d_out, int out_size, void* d_ws, size_t ws_size,
                              hipStream_t stream) {
    const int*   inp   = (const int*)d_in[0];
    const float* emb0  = (const float*)d_in[1];
    const float* proj0 = (const float*)d_in[2];
    const float* emb1  = (const float*)d_in[3];
    const float* proj1 = (const float*)d_in[4];
    const float* emb2  = (const float*)d_in[5];
    const float* proj2 = (const float*)d_in[6];
    const float* emb3  = (const float*)d_in[7];
    const float* proj3 = (const float*)d_in[8];
    float* out = (float*)d_out;
    const int T = in_sizes[0];   // 16384

    unsigned* counters = (unsigned*)d_ws;
    unsigned* lists    = (unsigned*)((char*)d_ws + 256);

    hipMemsetAsync(counters, 0, 16, stream);
    classify_kernel<<<dim3((T + 255) / 256), 256, 0, stream>>>(inp, counters, lists, T);

    // 2048 persistent blocks = 8/CU (LDS-bound); ~4100 real tiles grid-stride.
    gemm_fused<<<dim3(2048), 256, 0, stream>>>(emb0, proj0, emb1, proj1,
                                               emb2, proj2, emb3, proj3,
                                               lists, counters, T, out);
}